// Round 2
// baseline (567.256 us; speedup 1.0000x reference)
//
#include <hip/hip_runtime.h>
#include <hip/hip_bf16.h>

// LightGCN: 3 layers of SpMM on 200000x64 embeddings, 3.2M edges.
// R6: kill the f32 accumulator RMW (was 256MB of acc traffic across the
//     3 spmm layers; FETCH showed +51MB acc-read, WRITE +51MB acc-write per
//     non-first layer). Layers 0-1 now write only their bf16 y output;
//     layer 2's epilogue reads y1[r], y2[r] (bf16, sequential) and writes
//     out = (a + y1 + y2)/3 once. Net -179MB.
//     Also: nontemporal loads on the streamed `sorted` records and NT
//     stores on `out` (never re-read) so streams stop evicting gather
//     lines from L2; concat fused into hist_bucket (independent work).
// R5: two-level counting-sort CSR build (hist_bucket / scan_buckets /
//     bin_edges / sort_bucket) - scatter WRITE_SIZE 192MB -> ~30MB.

constexpr int NUM_USERS = 100000;
constexpr int NUM_ITEMS = 100000;
constexpr int N_NODES   = NUM_USERS + NUM_ITEMS;   // 200000
constexpr int EMB       = 64;
constexpr int N_EDGES   = 3200000;

constexpr int BUCK_SHIFT = 8;                       // 256 rows per bucket
constexpr int NBUCK = (N_NODES + 255) >> BUCK_SHIFT; // 782
constexpr int BIN_BLOCK = 512;
constexpr int EPB = 8192;                            // edges per bin block
constexpr int NBIN_BLOCKS = (N_EDGES + EPB - 1) / EPB; // 391
constexpr int SORT_CAP = 6144;                       // mean 4096, sigma 64

constexpr int HIST_BLOCKS   = 512;
constexpr int CONCAT_BLOCKS = (N_NODES * 8 + 255) / 256; // 6250

typedef int      i32x2 __attribute__((ext_vector_type(2)));
typedef unsigned u32x4 __attribute__((ext_vector_type(4)));
typedef float    f32x4 __attribute__((ext_vector_type(4)));

// ---------------- bf16 helpers ----------------

__device__ __forceinline__ float bfl(unsigned u) { return __uint_as_float(u << 16); }
__device__ __forceinline__ float bfh(unsigned u) { return __uint_as_float(u & 0xFFFF0000u); }
__device__ __forceinline__ unsigned f2bf(float f) {          // RNE
    unsigned u = __float_as_uint(f);
    return (u + 0x7FFFu + ((u >> 16) & 1u)) >> 16;
}
__device__ __forceinline__ unsigned pk(float lo, float hi) {
    return f2bf(lo) | (f2bf(hi) << 16);
}

// ---------------- prep: coarse histogram + concat->bf16 (fused, independent) ----------------

__global__ __launch_bounds__(256) void prep(
    const int* __restrict__ row, int* __restrict__ bcnt,
    const float4* __restrict__ u, const float4* __restrict__ it,
    uint4* __restrict__ ebuf) {
    __shared__ int h[NBUCK];
    if (blockIdx.x < HIST_BLOCKS) {
        for (int i = threadIdx.x; i < NBUCK; i += 256) h[i] = 0;
        __syncthreads();
        int nt = HIST_BLOCKS * 256;
        for (int e = blockIdx.x * 256 + threadIdx.x; e < N_EDGES; e += nt) {
            int r = __builtin_nontemporal_load(&row[e]);
            atomicAdd(&h[r >> BUCK_SHIFT], 1);
        }
        __syncthreads();
        for (int i = threadIdx.x; i < NBUCK; i += 256) {
            int c = h[i];
            if (c) atomicAdd(&bcnt[i], c);
        }
    } else {
        int i = (blockIdx.x - HIST_BLOCKS) * 256 + threadIdx.x;
        if (i >= N_NODES * 8) return;
        const float4* s = (i < NUM_USERS * 8) ? (u + 2 * (size_t)i)
                                              : (it + 2 * ((size_t)i - (size_t)NUM_USERS * 8));
        float4 f0 = s[0], f1 = s[1];
        uint4 o;
        o.x = pk(f0.x, f0.y); o.y = pk(f0.z, f0.w);
        o.z = pk(f1.x, f1.y); o.w = pk(f1.z, f1.w);
        ebuf[i] = o;
    }
}

// ---------------- CSR build: two-level counting sort ----------------

// Exclusive scan of 782 bucket counts -> bucket bases + cursors.
__global__ __launch_bounds__(1024) void scan_buckets(const int* __restrict__ bcnt,
                                                     int* __restrict__ bbase,
                                                     int* __restrict__ bcursor) {
    __shared__ int lds[1024];
    int t = threadIdx.x;
    int v = (t < NBUCK) ? bcnt[t] : 0;
    lds[t] = v;
    __syncthreads();
    for (int off = 1; off < 1024; off <<= 1) {
        int x = (t >= off) ? lds[t - off] : 0;
        __syncthreads();
        lds[t] += x;
        __syncthreads();
    }
    int excl = lds[t] - v;
    if (t < NBUCK) { bbase[t] = excl; bcursor[t] = excl; }
    if (t == 0) bbase[NBUCK] = N_EDGES;
}

// Bin edges into coarse buckets. Per-block LDS counting + one chunked
// atomic reservation per (block,bucket), then scatter packed records.
// Record: { col | (row&255)<<18 , w_bits }  (col < 2^18, rlow 8 bits).
__global__ __launch_bounds__(BIN_BLOCK) void bin_edges(
    const int* __restrict__ row, const int* __restrict__ col,
    const float* __restrict__ w,
    int* __restrict__ bcursor, int2* __restrict__ binned) {
    __shared__ int hcnt[NBUCK];
    __shared__ int hbase[NBUCK];
    int t = threadIdx.x;
    int e0 = blockIdx.x * EPB;
    int e1 = e0 + EPB; if (e1 > N_EDGES) e1 = N_EDGES;

    for (int i = t; i < NBUCK; i += BIN_BLOCK) hcnt[i] = 0;
    __syncthreads();
    for (int e = e0 + t; e < e1; e += BIN_BLOCK) {
        int r = __builtin_nontemporal_load(&row[e]);
        atomicAdd(&hcnt[r >> BUCK_SHIFT], 1);
    }
    __syncthreads();
    for (int i = t; i < NBUCK; i += BIN_BLOCK) {
        int c = hcnt[i];
        hbase[i] = c ? atomicAdd(&bcursor[i], c) : 0;
        hcnt[i] = 0;
    }
    __syncthreads();
    for (int e = e0 + t; e < e1; e += BIN_BLOCK) {
        int r  = row[e];                 // L2-hot (read in pass A)
        int bk = r >> BUCK_SHIFT;
        int rank = atomicAdd(&hcnt[bk], 1);
        int2 rec = make_int2(__builtin_nontemporal_load(&col[e]) | ((r & 255) << 18),
                             __float_as_int(__builtin_nontemporal_load(&w[e])));
        binned[hbase[bk] + rank] = rec;
    }
}

// One block per bucket. LDS counting sort by row-within-bucket,
// emits row_start, stages sorted records in LDS, coalesced streamout.
__global__ __launch_bounds__(256) void sort_bucket(
    const int* __restrict__ bbase, const int2* __restrict__ binned,
    int2* __restrict__ sorted, int* __restrict__ row_start) {
    __shared__ int cnt[256];
    __shared__ int sc[256];
    __shared__ int2 buf[SORT_CAP];
    int b = blockIdx.x, t = threadIdx.x;
    int gb = bbase[b];
    int n  = bbase[b + 1] - gb;

    cnt[t] = 0;
    __syncthreads();
    for (int i = t; i < n; i += 256)
        atomicAdd(&cnt[binned[gb + i].x >> 18], 1);
    __syncthreads();

    // exclusive scan of cnt[256]
    int v = cnt[t];
    sc[t] = v;
    __syncthreads();
    for (int off = 1; off < 256; off <<= 1) {
        int x = (t >= off) ? sc[t - off] : 0;
        __syncthreads();
        sc[t] += x;
        __syncthreads();
    }
    int excl = sc[t] - v;

    int r = (b << BUCK_SHIFT) + t;
    if (r < N_NODES) row_start[r] = gb + excl;
    if (b == NBUCK - 1 && t == 0) row_start[N_NODES] = N_EDGES;
    __syncthreads();
    cnt[t] = excl;                        // reuse as running cursor
    __syncthreads();

    for (int i = t; i < n; i += 256) {
        int2 rec = binned[gb + i];        // L2-hot (read in phase 1)
        int rl = rec.x >> 18;
        int k = atomicAdd(&cnt[rl], 1);
        if (k < SORT_CAP)
            buf[k] = make_int2(rec.x & 0x3FFFF, rec.y);
    }
    __syncthreads();
    int m = n < SORT_CAP ? n : SORT_CAP;
    for (int i = t; i < m; i += 256)
        sorted[gb + i] = buf[i];
}

// ---------------- SpMM: bf16 gather, 8-lane groups, 16 edges in flight ----------------
// LAST=false: write bf16 y only. LAST=true: no y; epilogue reads y1[r] and
// src[r] (=y2) and writes out = (a + y1 + y2)/3 (f32, NT).

template<bool LAST>
__global__ __launch_bounds__(256) void spmm_bf16(
    const int* __restrict__ row_start, const int2* __restrict__ sorted,
    const uint4* __restrict__ src,     // bf16 rows: 8 x uint4 per row
    uint4* __restrict__ y,             // bf16 rows out (!LAST)
    const uint4* __restrict__ y1,      // layer-1 output rows (LAST)
    f32x4* __restrict__ out)           // f32 final (LAST)
{
    int lane = threadIdx.x & 63;
    int r = blockIdx.x * 4 + (threadIdx.x >> 6);
    if (r >= N_NODES) return;
    int g = lane >> 3;        // edge group 0..7
    int s = lane & 7;         // 16B slot within row (8 bf16)
    int s0 = row_start[r];
    int s1 = row_start[r + 1];

    float a0 = 0.f, a1 = 0.f, a2 = 0.f, a3 = 0.f;
    float a4 = 0.f, a5 = 0.f, a6 = 0.f, a7 = 0.f;

    for (int base = s0; base < s1; base += 16) {
        int i0 = base + g;
        int i1 = base + 8 + g;
        if (i0 < s1) {
            i32x2 e = __builtin_nontemporal_load((const i32x2*)(sorted + i0));
            float wt = __int_as_float(e.y);
            uint4 v = src[(size_t)e.x * 8 + s];
            a0 = fmaf(wt, bfl(v.x), a0); a1 = fmaf(wt, bfh(v.x), a1);
            a2 = fmaf(wt, bfl(v.y), a2); a3 = fmaf(wt, bfh(v.y), a3);
            a4 = fmaf(wt, bfl(v.z), a4); a5 = fmaf(wt, bfh(v.z), a5);
            a6 = fmaf(wt, bfl(v.w), a6); a7 = fmaf(wt, bfh(v.w), a7);
        }
        if (i1 < s1) {
            i32x2 e = __builtin_nontemporal_load((const i32x2*)(sorted + i1));
            float wt = __int_as_float(e.y);
            uint4 v = src[(size_t)e.x * 8 + s];
            a0 = fmaf(wt, bfl(v.x), a0); a1 = fmaf(wt, bfh(v.x), a1);
            a2 = fmaf(wt, bfl(v.y), a2); a3 = fmaf(wt, bfh(v.y), a3);
            a4 = fmaf(wt, bfl(v.z), a4); a5 = fmaf(wt, bfh(v.z), a5);
            a6 = fmaf(wt, bfl(v.w), a6); a7 = fmaf(wt, bfh(v.w), a7);
        }
    }

    // reduce across the 8 edge groups (lane bits 3,4,5)
#define RED(m) \
    a0 += __shfl_xor(a0, m); a1 += __shfl_xor(a1, m); \
    a2 += __shfl_xor(a2, m); a3 += __shfl_xor(a3, m); \
    a4 += __shfl_xor(a4, m); a5 += __shfl_xor(a5, m); \
    a6 += __shfl_xor(a6, m); a7 += __shfl_xor(a7, m);
    RED(8) RED(16) RED(32)
#undef RED

    if (!LAST) {
        if (g == 0) {
            uint4 o;
            o.x = pk(a0, a1); o.y = pk(a2, a3);
            o.z = pk(a4, a5); o.w = pk(a6, a7);
            y[(size_t)r * 8 + s] = o;
        }
    } else {
        if (g == 0) {
            // read the two earlier layer outputs for this row (read-once, NT)
            u32x4 u1 = __builtin_nontemporal_load((const u32x4*)(y1 + (size_t)r * 8 + s));
            u32x4 u2 = __builtin_nontemporal_load((const u32x4*)(src + (size_t)r * 8 + s));
            constexpr float sc = 1.0f / 3.0f;
            f32x4 o0, o1;
            o0.x = (a0 + bfl(u1.x) + bfl(u2.x)) * sc;
            o0.y = (a1 + bfh(u1.x) + bfh(u2.x)) * sc;
            o0.z = (a2 + bfl(u1.y) + bfl(u2.y)) * sc;
            o0.w = (a3 + bfh(u1.y) + bfh(u2.y)) * sc;
            o1.x = (a4 + bfl(u1.z) + bfl(u2.z)) * sc;
            o1.y = (a5 + bfh(u1.z) + bfh(u2.z)) * sc;
            o1.z = (a6 + bfl(u1.w) + bfl(u2.w)) * sc;
            o1.w = (a7 + bfh(u1.w) + bfh(u2.w)) * sc;
            size_t ob = (size_t)r * 16 + 2 * s;
            __builtin_nontemporal_store(o0, out + ob);
            __builtin_nontemporal_store(o1, out + ob + 1);
        }
    }
}

// ---------------- launch ----------------

extern "C" void kernel_launch(void* const* d_in, const int* in_sizes, int n_in,
                              void* d_out, int out_size, void* d_ws, size_t ws_size,
                              hipStream_t stream) {
    const float* user_emb = (const float*)d_in[0];
    const float* item_emb = (const float*)d_in[1];
    const float* edge_w   = (const float*)d_in[2];
    const int*   edge_row = (const int*)d_in[3];
    const int*   edge_col = (const int*)d_in[4];

    // ws layout: two bf16 embedding buffers + CSR.
    // binned aliases ybuf (binned dead after sort_bucket; ybuf first written
    // by spmm layer 0, which runs after).
    char* p = (char*)d_ws;
    uint4* ebuf = (uint4*)p;        p += (size_t)N_NODES * 8 * sizeof(uint4);   // 25.6 MB
    uint4* ybuf = (uint4*)p;        p += (size_t)N_NODES * 8 * sizeof(uint4);   // 25.6 MB
    int2*  sorted = (int2*)p;       p += (size_t)N_EDGES * sizeof(int2);        // 25.6 MB
    int*   bcnt = (int*)p;          p += (size_t)NBUCK * sizeof(int);
    int*   bbase = (int*)p;         p += (size_t)(NBUCK + 1) * sizeof(int);
    int*   bcursor = (int*)p;       p += (size_t)NBUCK * sizeof(int);
    int*   row_start = (int*)p;     p += (size_t)(N_NODES + 1) * sizeof(int);
    int2*  binned = (int2*)ybuf;    // alias

    hipMemsetAsync(bcnt, 0, (size_t)NBUCK * sizeof(int), stream);

    // fused: coarse histogram (blocks 0..511) + concat->bf16 (rest)
    prep<<<HIST_BLOCKS + CONCAT_BLOCKS, 256, 0, stream>>>(
        edge_row, bcnt, (const float4*)user_emb, (const float4*)item_emb, ebuf);

    scan_buckets<<<1, 1024, 0, stream>>>(bcnt, bbase, bcursor);
    bin_edges<<<NBIN_BLOCKS, BIN_BLOCK, 0, stream>>>(edge_row, edge_col, edge_w,
                                                     bcursor, binned);
    sort_bucket<<<NBUCK, 256, 0, stream>>>(bbase, binned, sorted, row_start);

    int grid = (N_NODES + 3) / 4;                  // 4 rows per 256-thread block
    // layer 0: ebuf -> ybuf (y1)
    spmm_bf16<false><<<grid, 256, 0, stream>>>(row_start, sorted, ebuf, ybuf,
                                               nullptr, nullptr);
    // layer 1: ybuf -> ebuf (y2; ebuf dead after layer 0)
    spmm_bf16<false><<<grid, 256, 0, stream>>>(row_start, sorted, ybuf, ebuf,
                                               nullptr, nullptr);
    // layer 2: src=ebuf (y2), epilogue reads ybuf (y1) + ebuf rows, writes out
    spmm_bf16<true><<<grid, 256, 0, stream>>>(row_start, sorted, ebuf, nullptr,
                                              ybuf, (f32x4*)d_out);
}

// Round 3
// 500.197 us; speedup vs baseline: 1.1341x; 1.1341x over previous
//
#include <hip/hip_runtime.h>
#include <hip/hip_bf16.h>

// LightGCN: 3 layers of SpMM on 200000x64 embeddings, 3.2M edges.
// R7: post-mortem of R6 regression (539->567): NT loads on the `sorted`
//     stream / epilogue turned an L2-resident dependent load chain into
//     long-latency fetches (BW 2.97->2.31 TB/s, VALUBusy 49->37 at FEWER
//     bytes). Revert all NT inside spmm (plain loads/stores), KEEP the
//     R6 structural win: no f32 acc RMW - layers 0/1 write bf16 y only,
//     layer 2 fuses out=(a+y1+y2)/3. Also bin_edges EPB 8192->16384
//     (block 1024): per-(block,bucket) runs 84B->168B, halves partial-line
//     write amplification + reservation atomics.
// R5: two-level counting-sort CSR build (scatter WRITE 192MB -> ~30MB).

constexpr int NUM_USERS = 100000;
constexpr int NUM_ITEMS = 100000;
constexpr int N_NODES   = NUM_USERS + NUM_ITEMS;   // 200000
constexpr int EMB       = 64;
constexpr int N_EDGES   = 3200000;

constexpr int BUCK_SHIFT = 8;                       // 256 rows per bucket
constexpr int NBUCK = (N_NODES + 255) >> BUCK_SHIFT; // 782
constexpr int BIN_BLOCK = 1024;
constexpr int EPB = 16384;                           // edges per bin block
constexpr int NBIN_BLOCKS = (N_EDGES + EPB - 1) / EPB; // 196
constexpr int SORT_CAP = 6144;                       // mean 4096, sigma 64

constexpr int HIST_BLOCKS   = 512;
constexpr int CONCAT_BLOCKS = (N_NODES * 8 + 255) / 256; // 6250

// ---------------- bf16 helpers ----------------

__device__ __forceinline__ float bfl(unsigned u) { return __uint_as_float(u << 16); }
__device__ __forceinline__ float bfh(unsigned u) { return __uint_as_float(u & 0xFFFF0000u); }
__device__ __forceinline__ unsigned f2bf(float f) {          // RNE
    unsigned u = __float_as_uint(f);
    return (u + 0x7FFFu + ((u >> 16) & 1u)) >> 16;
}
__device__ __forceinline__ unsigned pk(float lo, float hi) {
    return f2bf(lo) | (f2bf(hi) << 16);
}

// ---------------- prep: coarse histogram + concat->bf16 (fused, independent) ----------------

__global__ __launch_bounds__(256) void prep(
    const int* __restrict__ row, int* __restrict__ bcnt,
    const float4* __restrict__ u, const float4* __restrict__ it,
    uint4* __restrict__ ebuf) {
    __shared__ int h[NBUCK];
    if (blockIdx.x < HIST_BLOCKS) {
        for (int i = threadIdx.x; i < NBUCK; i += 256) h[i] = 0;
        __syncthreads();
        int nt = HIST_BLOCKS * 256;
        for (int e = blockIdx.x * 256 + threadIdx.x; e < N_EDGES; e += nt) {
            int r = __builtin_nontemporal_load(&row[e]);
            atomicAdd(&h[r >> BUCK_SHIFT], 1);
        }
        __syncthreads();
        for (int i = threadIdx.x; i < NBUCK; i += 256) {
            int c = h[i];
            if (c) atomicAdd(&bcnt[i], c);
        }
    } else {
        int i = (blockIdx.x - HIST_BLOCKS) * 256 + threadIdx.x;
        if (i >= N_NODES * 8) return;
        const float4* s = (i < NUM_USERS * 8) ? (u + 2 * (size_t)i)
                                              : (it + 2 * ((size_t)i - (size_t)NUM_USERS * 8));
        float4 f0 = s[0], f1 = s[1];
        uint4 o;
        o.x = pk(f0.x, f0.y); o.y = pk(f0.z, f0.w);
        o.z = pk(f1.x, f1.y); o.w = pk(f1.z, f1.w);
        ebuf[i] = o;
    }
}

// ---------------- CSR build: two-level counting sort ----------------

// Exclusive scan of 782 bucket counts -> bucket bases + cursors.
__global__ __launch_bounds__(1024) void scan_buckets(const int* __restrict__ bcnt,
                                                     int* __restrict__ bbase,
                                                     int* __restrict__ bcursor) {
    __shared__ int lds[1024];
    int t = threadIdx.x;
    int v = (t < NBUCK) ? bcnt[t] : 0;
    lds[t] = v;
    __syncthreads();
    for (int off = 1; off < 1024; off <<= 1) {
        int x = (t >= off) ? lds[t - off] : 0;
        __syncthreads();
        lds[t] += x;
        __syncthreads();
    }
    int excl = lds[t] - v;
    if (t < NBUCK) { bbase[t] = excl; bcursor[t] = excl; }
    if (t == 0) bbase[NBUCK] = N_EDGES;
}

// Bin edges into coarse buckets. Per-block LDS counting + one chunked
// atomic reservation per (block,bucket), then scatter packed records.
// Record: { col | (row&255)<<18 , w_bits }  (col < 2^18, rlow 8 bits).
__global__ __launch_bounds__(BIN_BLOCK) void bin_edges(
    const int* __restrict__ row, const int* __restrict__ col,
    const float* __restrict__ w,
    int* __restrict__ bcursor, int2* __restrict__ binned) {
    __shared__ int hcnt[NBUCK];
    __shared__ int hbase[NBUCK];
    int t = threadIdx.x;
    int e0 = blockIdx.x * EPB;
    int e1 = e0 + EPB; if (e1 > N_EDGES) e1 = N_EDGES;

    for (int i = t; i < NBUCK; i += BIN_BLOCK) hcnt[i] = 0;
    __syncthreads();
    for (int e = e0 + t; e < e1; e += BIN_BLOCK) {
        int r = __builtin_nontemporal_load(&row[e]);
        atomicAdd(&hcnt[r >> BUCK_SHIFT], 1);
    }
    __syncthreads();
    for (int i = t; i < NBUCK; i += BIN_BLOCK) {
        int c = hcnt[i];
        hbase[i] = c ? atomicAdd(&bcursor[i], c) : 0;
        hcnt[i] = 0;
    }
    __syncthreads();
    for (int e = e0 + t; e < e1; e += BIN_BLOCK) {
        int r  = row[e];                 // L2-hot (read in pass A)
        int bk = r >> BUCK_SHIFT;
        int rank = atomicAdd(&hcnt[bk], 1);
        int2 rec = make_int2(__builtin_nontemporal_load(&col[e]) | ((r & 255) << 18),
                             __float_as_int(__builtin_nontemporal_load(&w[e])));
        binned[hbase[bk] + rank] = rec;
    }
}

// One block per bucket. LDS counting sort by row-within-bucket,
// emits row_start, stages sorted records in LDS, coalesced streamout.
__global__ __launch_bounds__(256) void sort_bucket(
    const int* __restrict__ bbase, const int2* __restrict__ binned,
    int2* __restrict__ sorted, int* __restrict__ row_start) {
    __shared__ int cnt[256];
    __shared__ int sc[256];
    __shared__ int2 buf[SORT_CAP];
    int b = blockIdx.x, t = threadIdx.x;
    int gb = bbase[b];
    int n  = bbase[b + 1] - gb;

    cnt[t] = 0;
    __syncthreads();
    for (int i = t; i < n; i += 256)
        atomicAdd(&cnt[binned[gb + i].x >> 18], 1);
    __syncthreads();

    // exclusive scan of cnt[256]
    int v = cnt[t];
    sc[t] = v;
    __syncthreads();
    for (int off = 1; off < 256; off <<= 1) {
        int x = (t >= off) ? sc[t - off] : 0;
        __syncthreads();
        sc[t] += x;
        __syncthreads();
    }
    int excl = sc[t] - v;

    int r = (b << BUCK_SHIFT) + t;
    if (r < N_NODES) row_start[r] = gb + excl;
    if (b == NBUCK - 1 && t == 0) row_start[N_NODES] = N_EDGES;
    __syncthreads();
    cnt[t] = excl;                        // reuse as running cursor
    __syncthreads();

    for (int i = t; i < n; i += 256) {
        int2 rec = binned[gb + i];        // L2-hot (read in phase 1)
        int rl = rec.x >> 18;
        int k = atomicAdd(&cnt[rl], 1);
        if (k < SORT_CAP)
            buf[k] = make_int2(rec.x & 0x3FFFF, rec.y);
    }
    __syncthreads();
    int m = n < SORT_CAP ? n : SORT_CAP;
    for (int i = t; i < m; i += 256)
        sorted[gb + i] = buf[i];
}

// ---------------- SpMM: bf16 gather, 8-lane groups, 16 edges in flight ----------------
// LAST=false: write bf16 y only. LAST=true: no y; epilogue reads y1[r] and
// src[r] (=y2) and writes out = (a + y1 + y2)/3 (f32).

template<bool LAST>
__global__ __launch_bounds__(256) void spmm_bf16(
    const int* __restrict__ row_start, const int2* __restrict__ sorted,
    const uint4* __restrict__ src,     // bf16 rows: 8 x uint4 per row
    uint4* __restrict__ y,             // bf16 rows out (!LAST)
    const uint4* __restrict__ y1,      // layer-1 output rows (LAST)
    float4* __restrict__ out)          // f32 final (LAST)
{
    int lane = threadIdx.x & 63;
    int r = blockIdx.x * 4 + (threadIdx.x >> 6);
    if (r >= N_NODES) return;
    int g = lane >> 3;        // edge group 0..7
    int s = lane & 7;         // 16B slot within row (8 bf16)
    int s0 = row_start[r];
    int s1 = row_start[r + 1];

    float a0 = 0.f, a1 = 0.f, a2 = 0.f, a3 = 0.f;
    float a4 = 0.f, a5 = 0.f, a6 = 0.f, a7 = 0.f;

    for (int base = s0; base < s1; base += 16) {
        int i0 = base + g;
        int i1 = base + 8 + g;
        if (i0 < s1) {
            int2 e = sorted[i0];
            float wt = __int_as_float(e.y);
            uint4 v = src[(size_t)e.x * 8 + s];
            a0 = fmaf(wt, bfl(v.x), a0); a1 = fmaf(wt, bfh(v.x), a1);
            a2 = fmaf(wt, bfl(v.y), a2); a3 = fmaf(wt, bfh(v.y), a3);
            a4 = fmaf(wt, bfl(v.z), a4); a5 = fmaf(wt, bfh(v.z), a5);
            a6 = fmaf(wt, bfl(v.w), a6); a7 = fmaf(wt, bfh(v.w), a7);
        }
        if (i1 < s1) {
            int2 e = sorted[i1];
            float wt = __int_as_float(e.y);
            uint4 v = src[(size_t)e.x * 8 + s];
            a0 = fmaf(wt, bfl(v.x), a0); a1 = fmaf(wt, bfh(v.x), a1);
            a2 = fmaf(wt, bfl(v.y), a2); a3 = fmaf(wt, bfh(v.y), a3);
            a4 = fmaf(wt, bfl(v.z), a4); a5 = fmaf(wt, bfh(v.z), a5);
            a6 = fmaf(wt, bfl(v.w), a6); a7 = fmaf(wt, bfh(v.w), a7);
        }
    }

    // reduce across the 8 edge groups (lane bits 3,4,5)
#define RED(m) \
    a0 += __shfl_xor(a0, m); a1 += __shfl_xor(a1, m); \
    a2 += __shfl_xor(a2, m); a3 += __shfl_xor(a3, m); \
    a4 += __shfl_xor(a4, m); a5 += __shfl_xor(a5, m); \
    a6 += __shfl_xor(a6, m); a7 += __shfl_xor(a7, m);
    RED(8) RED(16) RED(32)
#undef RED

    if (!LAST) {
        if (g == 0) {
            uint4 o;
            o.x = pk(a0, a1); o.y = pk(a2, a3);
            o.z = pk(a4, a5); o.w = pk(a6, a7);
            y[(size_t)r * 8 + s] = o;
        }
    } else {
        if (g == 0) {
            // read the two earlier layer outputs for this row (read-once)
            uint4 u1 = y1[(size_t)r * 8 + s];
            uint4 u2 = src[(size_t)r * 8 + s];
            constexpr float sc = 1.0f / 3.0f;
            float4 o0, o1;
            o0.x = (a0 + bfl(u1.x) + bfl(u2.x)) * sc;
            o0.y = (a1 + bfh(u1.x) + bfh(u2.x)) * sc;
            o0.z = (a2 + bfl(u1.y) + bfl(u2.y)) * sc;
            o0.w = (a3 + bfh(u1.y) + bfh(u2.y)) * sc;
            o1.x = (a4 + bfl(u1.z) + bfl(u2.z)) * sc;
            o1.y = (a5 + bfh(u1.z) + bfh(u2.z)) * sc;
            o1.z = (a6 + bfl(u1.w) + bfl(u2.w)) * sc;
            o1.w = (a7 + bfh(u1.w) + bfh(u2.w)) * sc;
            size_t ob = (size_t)r * 16 + 2 * s;
            out[ob]     = o0;
            out[ob + 1] = o1;
        }
    }
}

// ---------------- launch ----------------

extern "C" void kernel_launch(void* const* d_in, const int* in_sizes, int n_in,
                              void* d_out, int out_size, void* d_ws, size_t ws_size,
                              hipStream_t stream) {
    const float* user_emb = (const float*)d_in[0];
    const float* item_emb = (const float*)d_in[1];
    const float* edge_w   = (const float*)d_in[2];
    const int*   edge_row = (const int*)d_in[3];
    const int*   edge_col = (const int*)d_in[4];

    // ws layout: two bf16 embedding buffers + CSR.
    // binned aliases ybuf (binned dead after sort_bucket; ybuf first written
    // by spmm layer 0, which runs after).
    char* p = (char*)d_ws;
    uint4* ebuf = (uint4*)p;        p += (size_t)N_NODES * 8 * sizeof(uint4);   // 25.6 MB
    uint4* ybuf = (uint4*)p;        p += (size_t)N_NODES * 8 * sizeof(uint4);   // 25.6 MB
    int2*  sorted = (int2*)p;       p += (size_t)N_EDGES * sizeof(int2);        // 25.6 MB
    int*   bcnt = (int*)p;          p += (size_t)NBUCK * sizeof(int);
    int*   bbase = (int*)p;         p += (size_t)(NBUCK + 1) * sizeof(int);
    int*   bcursor = (int*)p;       p += (size_t)NBUCK * sizeof(int);
    int*   row_start = (int*)p;     p += (size_t)(N_NODES + 1) * sizeof(int);
    int2*  binned = (int2*)ybuf;    // alias

    hipMemsetAsync(bcnt, 0, (size_t)NBUCK * sizeof(int), stream);

    // fused: coarse histogram (blocks 0..511) + concat->bf16 (rest)
    prep<<<HIST_BLOCKS + CONCAT_BLOCKS, 256, 0, stream>>>(
        edge_row, bcnt, (const float4*)user_emb, (const float4*)item_emb, ebuf);

    scan_buckets<<<1, 1024, 0, stream>>>(bcnt, bbase, bcursor);
    bin_edges<<<NBIN_BLOCKS, BIN_BLOCK, 0, stream>>>(edge_row, edge_col, edge_w,
                                                     bcursor, binned);
    sort_bucket<<<NBUCK, 256, 0, stream>>>(bbase, binned, sorted, row_start);

    int grid = (N_NODES + 3) / 4;                  // 4 rows per 256-thread block
    // layer 0: ebuf -> ybuf (y1)
    spmm_bf16<false><<<grid, 256, 0, stream>>>(row_start, sorted, ebuf, ybuf,
                                               nullptr, nullptr);
    // layer 1: ybuf -> ebuf (y2; ebuf dead after layer 0)
    spmm_bf16<false><<<grid, 256, 0, stream>>>(row_start, sorted, ybuf, ebuf,
                                               nullptr, nullptr);
    // layer 2: src=ebuf (y2), epilogue reads ybuf (y1) + ebuf rows, writes out
    spmm_bf16<true><<<grid, 256, 0, stream>>>(row_start, sorted, ebuf, nullptr,
                                              ybuf, (float4*)d_out);
}

// Round 4
// 432.254 us; speedup vs baseline: 1.3123x; 1.1572x over previous
//
#include <hip/hip_runtime.h>
#include <hip/hip_bf16.h>

// LightGCN: 3 layers of SpMM on 200000x64 embeddings, 3.2M edges.
// R8: spmm restructure for MLP. Old: wave-per-row, 8 edge-groups + 24-shfl
//     reduce tree -> ~2 gathers in flight/wave, 7200-cyc wave lifetime
//     (latency-bound: 2.78 TB/s fabric, VALUBusy 46%). New: 8-lane group
//     owns ONE row (lane = 16B slot), 4-deep unrolled unconditional edge
//     loop (tail slots -> col 0, wt=0; row 0 stays L2-hot so tails free).
//     32 gathers in flight/wave, no shuffles, 8x fewer waves, y-stores
//     1KB-contiguous per wave. CSR build unchanged from R7.
// R7: no-NT spmm + no f32 acc RMW (layer2 fuses out=(a+y1+y2)/3).
// R5: two-level counting-sort CSR build (scatter WRITE 192MB -> ~30MB).

constexpr int NUM_USERS = 100000;
constexpr int NUM_ITEMS = 100000;
constexpr int N_NODES   = NUM_USERS + NUM_ITEMS;   // 200000
constexpr int EMB       = 64;
constexpr int N_EDGES   = 3200000;

constexpr int BUCK_SHIFT = 8;                       // 256 rows per bucket
constexpr int NBUCK = (N_NODES + 255) >> BUCK_SHIFT; // 782
constexpr int BIN_BLOCK = 1024;
constexpr int EPB = 16384;                           // edges per bin block
constexpr int NBIN_BLOCKS = (N_EDGES + EPB - 1) / EPB; // 196
constexpr int SORT_CAP = 6144;                       // mean 4096, sigma 64

constexpr int HIST_BLOCKS   = 512;
constexpr int CONCAT_BLOCKS = (N_NODES * 8 + 255) / 256; // 6250

// ---------------- bf16 helpers ----------------

__device__ __forceinline__ float bfl(unsigned u) { return __uint_as_float(u << 16); }
__device__ __forceinline__ float bfh(unsigned u) { return __uint_as_float(u & 0xFFFF0000u); }
__device__ __forceinline__ unsigned f2bf(float f) {          // RNE
    unsigned u = __float_as_uint(f);
    return (u + 0x7FFFu + ((u >> 16) & 1u)) >> 16;
}
__device__ __forceinline__ unsigned pk(float lo, float hi) {
    return f2bf(lo) | (f2bf(hi) << 16);
}

// ---------------- prep: coarse histogram + concat->bf16 (fused, independent) ----------------

__global__ __launch_bounds__(256) void prep(
    const int* __restrict__ row, int* __restrict__ bcnt,
    const float4* __restrict__ u, const float4* __restrict__ it,
    uint4* __restrict__ ebuf) {
    __shared__ int h[NBUCK];
    if (blockIdx.x < HIST_BLOCKS) {
        for (int i = threadIdx.x; i < NBUCK; i += 256) h[i] = 0;
        __syncthreads();
        int nt = HIST_BLOCKS * 256;
        for (int e = blockIdx.x * 256 + threadIdx.x; e < N_EDGES; e += nt) {
            int r = __builtin_nontemporal_load(&row[e]);
            atomicAdd(&h[r >> BUCK_SHIFT], 1);
        }
        __syncthreads();
        for (int i = threadIdx.x; i < NBUCK; i += 256) {
            int c = h[i];
            if (c) atomicAdd(&bcnt[i], c);
        }
    } else {
        int i = (blockIdx.x - HIST_BLOCKS) * 256 + threadIdx.x;
        if (i >= N_NODES * 8) return;
        const float4* s = (i < NUM_USERS * 8) ? (u + 2 * (size_t)i)
                                              : (it + 2 * ((size_t)i - (size_t)NUM_USERS * 8));
        float4 f0 = s[0], f1 = s[1];
        uint4 o;
        o.x = pk(f0.x, f0.y); o.y = pk(f0.z, f0.w);
        o.z = pk(f1.x, f1.y); o.w = pk(f1.z, f1.w);
        ebuf[i] = o;
    }
}

// ---------------- CSR build: two-level counting sort ----------------

// Exclusive scan of 782 bucket counts -> bucket bases + cursors.
__global__ __launch_bounds__(1024) void scan_buckets(const int* __restrict__ bcnt,
                                                     int* __restrict__ bbase,
                                                     int* __restrict__ bcursor) {
    __shared__ int lds[1024];
    int t = threadIdx.x;
    int v = (t < NBUCK) ? bcnt[t] : 0;
    lds[t] = v;
    __syncthreads();
    for (int off = 1; off < 1024; off <<= 1) {
        int x = (t >= off) ? lds[t - off] : 0;
        __syncthreads();
        lds[t] += x;
        __syncthreads();
    }
    int excl = lds[t] - v;
    if (t < NBUCK) { bbase[t] = excl; bcursor[t] = excl; }
    if (t == 0) bbase[NBUCK] = N_EDGES;
}

// Bin edges into coarse buckets. Per-block LDS counting + one chunked
// atomic reservation per (block,bucket), then scatter packed records.
// Record: { col | (row&255)<<18 , w_bits }  (col < 2^18, rlow 8 bits).
__global__ __launch_bounds__(BIN_BLOCK) void bin_edges(
    const int* __restrict__ row, const int* __restrict__ col,
    const float* __restrict__ w,
    int* __restrict__ bcursor, int2* __restrict__ binned) {
    __shared__ int hcnt[NBUCK];
    __shared__ int hbase[NBUCK];
    int t = threadIdx.x;
    int e0 = blockIdx.x * EPB;
    int e1 = e0 + EPB; if (e1 > N_EDGES) e1 = N_EDGES;

    for (int i = t; i < NBUCK; i += BIN_BLOCK) hcnt[i] = 0;
    __syncthreads();
    for (int e = e0 + t; e < e1; e += BIN_BLOCK) {
        int r = __builtin_nontemporal_load(&row[e]);
        atomicAdd(&hcnt[r >> BUCK_SHIFT], 1);
    }
    __syncthreads();
    for (int i = t; i < NBUCK; i += BIN_BLOCK) {
        int c = hcnt[i];
        hbase[i] = c ? atomicAdd(&bcursor[i], c) : 0;
        hcnt[i] = 0;
    }
    __syncthreads();
    for (int e = e0 + t; e < e1; e += BIN_BLOCK) {
        int r  = row[e];                 // L2-hot (read in pass A)
        int bk = r >> BUCK_SHIFT;
        int rank = atomicAdd(&hcnt[bk], 1);
        int2 rec = make_int2(__builtin_nontemporal_load(&col[e]) | ((r & 255) << 18),
                             __float_as_int(__builtin_nontemporal_load(&w[e])));
        binned[hbase[bk] + rank] = rec;
    }
}

// One block per bucket. LDS counting sort by row-within-bucket,
// emits row_start, stages sorted records in LDS, coalesced streamout.
__global__ __launch_bounds__(256) void sort_bucket(
    const int* __restrict__ bbase, const int2* __restrict__ binned,
    int2* __restrict__ sorted, int* __restrict__ row_start) {
    __shared__ int cnt[256];
    __shared__ int sc[256];
    __shared__ int2 buf[SORT_CAP];
    int b = blockIdx.x, t = threadIdx.x;
    int gb = bbase[b];
    int n  = bbase[b + 1] - gb;

    cnt[t] = 0;
    __syncthreads();
    for (int i = t; i < n; i += 256)
        atomicAdd(&cnt[binned[gb + i].x >> 18], 1);
    __syncthreads();

    // exclusive scan of cnt[256]
    int v = cnt[t];
    sc[t] = v;
    __syncthreads();
    for (int off = 1; off < 256; off <<= 1) {
        int x = (t >= off) ? sc[t - off] : 0;
        __syncthreads();
        sc[t] += x;
        __syncthreads();
    }
    int excl = sc[t] - v;

    int r = (b << BUCK_SHIFT) + t;
    if (r < N_NODES) row_start[r] = gb + excl;
    if (b == NBUCK - 1 && t == 0) row_start[N_NODES] = N_EDGES;
    __syncthreads();
    cnt[t] = excl;                        // reuse as running cursor
    __syncthreads();

    for (int i = t; i < n; i += 256) {
        int2 rec = binned[gb + i];        // L2-hot (read in phase 1)
        int rl = rec.x >> 18;
        int k = atomicAdd(&cnt[rl], 1);
        if (k < SORT_CAP)
            buf[k] = make_int2(rec.x & 0x3FFFF, rec.y);
    }
    __syncthreads();
    int m = n < SORT_CAP ? n : SORT_CAP;
    for (int i = t; i < m; i += 256)
        sorted[gb + i] = buf[i];
}

// ---------------- SpMM: 8-lane group per row, 4-deep unrolled gather ----------------
// Each 8-thread group owns one destination row; lane s covers bytes
// [16s,16s+16) of the 128B row. Edge loop is unconditional 4-wide: tail
// slots load a clamped record but get col=0 / wt=0 (row 0 stays L2-hot).
// LAST=false: write bf16 y. LAST=true: out = (a + y1[r] + src[r]) / 3.

template<bool LAST>
__global__ __launch_bounds__(256) void spmm_bf16(
    const int* __restrict__ row_start, const int2* __restrict__ sorted,
    const uint4* __restrict__ src,     // bf16 rows: 8 x uint4 per row
    uint4* __restrict__ y,             // bf16 rows out (!LAST)
    const uint4* __restrict__ y1,      // layer-1 output rows (LAST)
    float4* __restrict__ out)          // f32 final (LAST)
{
    int r = (blockIdx.x * blockDim.x + threadIdx.x) >> 3;
    int s = threadIdx.x & 7;           // 16B slot within row
    if (r >= N_NODES) return;
    int s0 = row_start[r];
    int s1 = row_start[r + 1];

    float a0 = 0.f, a1 = 0.f, a2 = 0.f, a3 = 0.f;
    float a4 = 0.f, a5 = 0.f, a6 = 0.f, a7 = 0.f;

    for (int base = s0; base < s1; base += 4) {
        // clamped record loads (always in-bounds), then tail-neutralized
        int i0 = base;
        int i1 = min(base + 1, N_EDGES - 1);
        int i2 = min(base + 2, N_EDGES - 1);
        int i3 = min(base + 3, N_EDGES - 1);
        int2 e0 = sorted[i0];
        int2 e1 = sorted[i1];
        int2 e2 = sorted[i2];
        int2 e3 = sorted[i3];
        bool v1 = base + 1 < s1, v2 = base + 2 < s1, v3 = base + 3 < s1;
        int   c0 = e0.x;
        int   c1 = v1 ? e1.x : 0;
        int   c2 = v2 ? e2.x : 0;
        int   c3 = v3 ? e3.x : 0;
        float w0 = __int_as_float(e0.y);
        float w1 = v1 ? __int_as_float(e1.y) : 0.f;
        float w2 = v2 ? __int_as_float(e2.y) : 0.f;
        float w3 = v3 ? __int_as_float(e3.y) : 0.f;
        uint4 g0 = src[(size_t)c0 * 8 + s];
        uint4 g1 = src[(size_t)c1 * 8 + s];
        uint4 g2 = src[(size_t)c2 * 8 + s];
        uint4 g3 = src[(size_t)c3 * 8 + s];
#define ACC(vv, wt) \
        a0 = fmaf(wt, bfl(vv.x), a0); a1 = fmaf(wt, bfh(vv.x), a1); \
        a2 = fmaf(wt, bfl(vv.y), a2); a3 = fmaf(wt, bfh(vv.y), a3); \
        a4 = fmaf(wt, bfl(vv.z), a4); a5 = fmaf(wt, bfh(vv.z), a5); \
        a6 = fmaf(wt, bfl(vv.w), a6); a7 = fmaf(wt, bfh(vv.w), a7);
        ACC(g0, w0) ACC(g1, w1) ACC(g2, w2) ACC(g3, w3)
#undef ACC
    }

    if (!LAST) {
        uint4 o;
        o.x = pk(a0, a1); o.y = pk(a2, a3);
        o.z = pk(a4, a5); o.w = pk(a6, a7);
        y[(size_t)r * 8 + s] = o;
    } else {
        // read the two earlier layer outputs for this row (read-once)
        uint4 u1 = y1[(size_t)r * 8 + s];
        uint4 u2 = src[(size_t)r * 8 + s];
        constexpr float sc = 1.0f / 3.0f;
        float4 o0, o1;
        o0.x = (a0 + bfl(u1.x) + bfl(u2.x)) * sc;
        o0.y = (a1 + bfh(u1.x) + bfh(u2.x)) * sc;
        o0.z = (a2 + bfl(u1.y) + bfl(u2.y)) * sc;
        o0.w = (a3 + bfh(u1.y) + bfh(u2.y)) * sc;
        o1.x = (a4 + bfl(u1.z) + bfl(u2.z)) * sc;
        o1.y = (a5 + bfh(u1.z) + bfh(u2.z)) * sc;
        o1.z = (a6 + bfl(u1.w) + bfl(u2.w)) * sc;
        o1.w = (a7 + bfh(u1.w) + bfh(u2.w)) * sc;
        size_t ob = (size_t)r * 16 + 2 * s;
        out[ob]     = o0;
        out[ob + 1] = o1;
    }
}

// ---------------- launch ----------------

extern "C" void kernel_launch(void* const* d_in, const int* in_sizes, int n_in,
                              void* d_out, int out_size, void* d_ws, size_t ws_size,
                              hipStream_t stream) {
    const float* user_emb = (const float*)d_in[0];
    const float* item_emb = (const float*)d_in[1];
    const float* edge_w   = (const float*)d_in[2];
    const int*   edge_row = (const int*)d_in[3];
    const int*   edge_col = (const int*)d_in[4];

    // ws layout: two bf16 embedding buffers + CSR.
    // binned aliases ybuf (binned dead after sort_bucket; ybuf first written
    // by spmm layer 0, which runs after).
    char* p = (char*)d_ws;
    uint4* ebuf = (uint4*)p;        p += (size_t)N_NODES * 8 * sizeof(uint4);   // 25.6 MB
    uint4* ybuf = (uint4*)p;        p += (size_t)N_NODES * 8 * sizeof(uint4);   // 25.6 MB
    int2*  sorted = (int2*)p;       p += (size_t)N_EDGES * sizeof(int2);        // 25.6 MB
    int*   bcnt = (int*)p;          p += (size_t)NBUCK * sizeof(int);
    int*   bbase = (int*)p;         p += (size_t)(NBUCK + 1) * sizeof(int);
    int*   bcursor = (int*)p;       p += (size_t)NBUCK * sizeof(int);
    int*   row_start = (int*)p;     p += (size_t)(N_NODES + 1) * sizeof(int);
    int2*  binned = (int2*)ybuf;    // alias

    hipMemsetAsync(bcnt, 0, (size_t)NBUCK * sizeof(int), stream);

    // fused: coarse histogram (blocks 0..511) + concat->bf16 (rest)
    prep<<<HIST_BLOCKS + CONCAT_BLOCKS, 256, 0, stream>>>(
        edge_row, bcnt, (const float4*)user_emb, (const float4*)item_emb, ebuf);

    scan_buckets<<<1, 1024, 0, stream>>>(bcnt, bbase, bcursor);
    bin_edges<<<NBIN_BLOCKS, BIN_BLOCK, 0, stream>>>(edge_row, edge_col, edge_w,
                                                     bcursor, binned);
    sort_bucket<<<NBUCK, 256, 0, stream>>>(bbase, binned, sorted, row_start);

    int grid = (N_NODES * 8 + 255) / 256;          // 32 rows per 256-thread block
    // layer 0: ebuf -> ybuf (y1)
    spmm_bf16<false><<<grid, 256, 0, stream>>>(row_start, sorted, ebuf, ybuf,
                                               nullptr, nullptr);
    // layer 1: ybuf -> ebuf (y2; ebuf dead after layer 0)
    spmm_bf16<false><<<grid, 256, 0, stream>>>(row_start, sorted, ybuf, ebuf,
                                               nullptr, nullptr);
    // layer 2: src=ebuf (y2), epilogue reads ybuf (y1) + ebuf rows, writes out
    spmm_bf16<true><<<grid, 256, 0, stream>>>(row_start, sorted, ebuf, nullptr,
                                              ybuf, (float4*)d_out);
}

// Round 5
// 416.064 us; speedup vs baseline: 1.3634x; 1.0389x over previous
//
#include <hip/hip_runtime.h>
#include <hip/hip_bf16.h>

// LightGCN: 3 layers of SpMM on 200000x64 embeddings, 3.2M edges.
// R9: bin_edges rework. Old: 3.2M scattered 8B global stores into ~168B
//     runs -> 64 L2 transactions per wave-store, partial lines bouncing
//     across XCDs (WRITE 75MB = 3x ideal, 75us, VALU 2%, occ 30%).
//     New: block-local counting sort by bucket in LDS (stage 8192 recs,
//     64KB), then flush each (block,bucket) run with 8 lanes x 8B
//     consecutive -> 64B-coalesced mostly-full-line writes. EPB 16384->8192
//     (512 thr, ~77KB LDS, 2 blocks/CU, 391 blocks -> all CUs busy).
// R8: spmm 8-lane-group-per-row, 4-deep unrolled gather (MLP fix).
// R7: no-NT spmm + no f32 acc RMW (layer2 fuses out=(a+y1+y2)/3).
// R5: two-level counting-sort CSR build.

constexpr int NUM_USERS = 100000;
constexpr int NUM_ITEMS = 100000;
constexpr int N_NODES   = NUM_USERS + NUM_ITEMS;   // 200000
constexpr int EMB       = 64;
constexpr int N_EDGES   = 3200000;

constexpr int BUCK_SHIFT = 8;                       // 256 rows per bucket
constexpr int NBUCK = (N_NODES + 255) >> BUCK_SHIFT; // 782
constexpr int BIN_BLOCK = 512;
constexpr int EPB = 8192;                            // edges per bin block
constexpr int NBIN_BLOCKS = (N_EDGES + EPB - 1) / EPB; // 391
constexpr int SORT_CAP = 6144;                       // mean 4096, sigma 64

constexpr int HIST_BLOCKS   = 512;
constexpr int CONCAT_BLOCKS = (N_NODES * 8 + 255) / 256; // 6250

// ---------------- bf16 helpers ----------------

__device__ __forceinline__ float bfl(unsigned u) { return __uint_as_float(u << 16); }
__device__ __forceinline__ float bfh(unsigned u) { return __uint_as_float(u & 0xFFFF0000u); }
__device__ __forceinline__ unsigned f2bf(float f) {          // RNE
    unsigned u = __float_as_uint(f);
    return (u + 0x7FFFu + ((u >> 16) & 1u)) >> 16;
}
__device__ __forceinline__ unsigned pk(float lo, float hi) {
    return f2bf(lo) | (f2bf(hi) << 16);
}

// ---------------- prep: coarse histogram + concat->bf16 (fused, independent) ----------------

__global__ __launch_bounds__(256) void prep(
    const int* __restrict__ row, int* __restrict__ bcnt,
    const float4* __restrict__ u, const float4* __restrict__ it,
    uint4* __restrict__ ebuf) {
    __shared__ int h[NBUCK];
    if (blockIdx.x < HIST_BLOCKS) {
        for (int i = threadIdx.x; i < NBUCK; i += 256) h[i] = 0;
        __syncthreads();
        int nt = HIST_BLOCKS * 256;
        for (int e = blockIdx.x * 256 + threadIdx.x; e < N_EDGES; e += nt) {
            int r = __builtin_nontemporal_load(&row[e]);
            atomicAdd(&h[r >> BUCK_SHIFT], 1);
        }
        __syncthreads();
        for (int i = threadIdx.x; i < NBUCK; i += 256) {
            int c = h[i];
            if (c) atomicAdd(&bcnt[i], c);
        }
    } else {
        int i = (blockIdx.x - HIST_BLOCKS) * 256 + threadIdx.x;
        if (i >= N_NODES * 8) return;
        const float4* s = (i < NUM_USERS * 8) ? (u + 2 * (size_t)i)
                                              : (it + 2 * ((size_t)i - (size_t)NUM_USERS * 8));
        float4 f0 = s[0], f1 = s[1];
        uint4 o;
        o.x = pk(f0.x, f0.y); o.y = pk(f0.z, f0.w);
        o.z = pk(f1.x, f1.y); o.w = pk(f1.z, f1.w);
        ebuf[i] = o;
    }
}

// ---------------- CSR build: two-level counting sort ----------------

// Exclusive scan of 782 bucket counts -> bucket bases + cursors.
__global__ __launch_bounds__(1024) void scan_buckets(const int* __restrict__ bcnt,
                                                     int* __restrict__ bbase,
                                                     int* __restrict__ bcursor) {
    __shared__ int lds[1024];
    int t = threadIdx.x;
    int v = (t < NBUCK) ? bcnt[t] : 0;
    lds[t] = v;
    __syncthreads();
    for (int off = 1; off < 1024; off <<= 1) {
        int x = (t >= off) ? lds[t - off] : 0;
        __syncthreads();
        lds[t] += x;
        __syncthreads();
    }
    int excl = lds[t] - v;
    if (t < NBUCK) { bbase[t] = excl; bcursor[t] = excl; }
    if (t == 0) bbase[NBUCK] = N_EDGES;
}

// Bin edges into coarse buckets, block-local counting sort in LDS:
//   A) local bucket histogram (hcnt)
//   B) global reservation (hbase, one atomic per non-empty bucket) +
//      local exclusive scan (cursor = local staging base)
//   C) stage records into LDS sorted by bucket (rank via LDS atomic)
//   D) flush: 8 lanes per bucket, consecutive 8B/lane -> coalesced lines
// Record: { col | (row&255)<<18 , w_bits }  (col < 2^18, rlow 8 bits).
__global__ __launch_bounds__(BIN_BLOCK) void bin_edges(
    const int* __restrict__ row, const int* __restrict__ col,
    const float* __restrict__ w,
    int* __restrict__ bcursor, int2* __restrict__ binned) {
    __shared__ int2 stage[EPB];          // 64 KB
    __shared__ int  hcnt[NBUCK];
    __shared__ int  hbase[NBUCK];
    __shared__ int  cursor[NBUCK];
    __shared__ int  lds2[BIN_BLOCK];
    int t = threadIdx.x;
    int e0 = blockIdx.x * EPB;
    int e1 = e0 + EPB; if (e1 > N_EDGES) e1 = N_EDGES;

    // A) local histogram (plain row load so chunk stays L2-hot for phase C)
    for (int i = t; i < NBUCK; i += BIN_BLOCK) hcnt[i] = 0;
    __syncthreads();
    for (int e = e0 + t; e < e1; e += BIN_BLOCK)
        atomicAdd(&hcnt[row[e] >> BUCK_SHIFT], 1);
    __syncthreads();

    // B1) global reservation
    for (int i = t; i < NBUCK; i += BIN_BLOCK) {
        int c = hcnt[i];
        hbase[i] = c ? atomicAdd(&bcursor[i], c) : 0;
    }
    // B2) local exclusive scan of hcnt -> cursor (pairs of 2 per thread)
    int i0 = 2 * t, i1 = 2 * t + 1;
    int c0 = (i0 < NBUCK) ? hcnt[i0] : 0;
    int c1 = (i1 < NBUCK) ? hcnt[i1] : 0;
    lds2[t] = c0 + c1;
    __syncthreads();
    for (int off = 1; off < BIN_BLOCK; off <<= 1) {
        int x = (t >= off) ? lds2[t - off] : 0;
        __syncthreads();
        lds2[t] += x;
        __syncthreads();
    }
    int pairExcl = lds2[t] - (c0 + c1);
    if (i0 < NBUCK) cursor[i0] = pairExcl;
    if (i1 < NBUCK) cursor[i1] = pairExcl + c0;
    __syncthreads();

    // C) stage records sorted by bucket
    for (int e = e0 + t; e < e1; e += BIN_BLOCK) {
        int r  = row[e];                 // L2-hot
        int bk = r >> BUCK_SHIFT;
        int pos = atomicAdd(&cursor[bk], 1);
        stage[pos] = make_int2(__builtin_nontemporal_load(&col[e]) | ((r & 255) << 18),
                               __float_as_int(__builtin_nontemporal_load(&w[e])));
    }
    __syncthreads();

    // D) flush runs: 8 lanes per bucket, 8 buckets per wave
    int wave = t >> 6;
    int lane = t & 63;
    int sl   = lane & 7;
    constexpr int NWAVE = BIN_BLOCK / 64;
    for (int base = wave * 8; base < NBUCK; base += NWAVE * 8) {
        int bk = base + (lane >> 3);
        if (bk < NBUCK) {
            int c  = hcnt[bk];
            int st = cursor[bk] - c;     // cursor now = local end
            int gp = hbase[bk];
            for (int j = sl; j < c; j += 8)
                binned[gp + j] = stage[st + j];
        }
    }
}

// One block per bucket. LDS counting sort by row-within-bucket,
// emits row_start, stages sorted records in LDS, coalesced streamout.
__global__ __launch_bounds__(256) void sort_bucket(
    const int* __restrict__ bbase, const int2* __restrict__ binned,
    int2* __restrict__ sorted, int* __restrict__ row_start) {
    __shared__ int cnt[256];
    __shared__ int sc[256];
    __shared__ int2 buf[SORT_CAP];
    int b = blockIdx.x, t = threadIdx.x;
    int gb = bbase[b];
    int n  = bbase[b + 1] - gb;

    cnt[t] = 0;
    __syncthreads();
    for (int i = t; i < n; i += 256)
        atomicAdd(&cnt[binned[gb + i].x >> 18], 1);
    __syncthreads();

    // exclusive scan of cnt[256]
    int v = cnt[t];
    sc[t] = v;
    __syncthreads();
    for (int off = 1; off < 256; off <<= 1) {
        int x = (t >= off) ? sc[t - off] : 0;
        __syncthreads();
        sc[t] += x;
        __syncthreads();
    }
    int excl = sc[t] - v;

    int r = (b << BUCK_SHIFT) + t;
    if (r < N_NODES) row_start[r] = gb + excl;
    if (b == NBUCK - 1 && t == 0) row_start[N_NODES] = N_EDGES;
    __syncthreads();
    cnt[t] = excl;                        // reuse as running cursor
    __syncthreads();

    for (int i = t; i < n; i += 256) {
        int2 rec = binned[gb + i];        // L2-hot (read in phase 1)
        int rl = rec.x >> 18;
        int k = atomicAdd(&cnt[rl], 1);
        if (k < SORT_CAP)
            buf[k] = make_int2(rec.x & 0x3FFFF, rec.y);
    }
    __syncthreads();
    int m = n < SORT_CAP ? n : SORT_CAP;
    for (int i = t; i < m; i += 256)
        sorted[gb + i] = buf[i];
}

// ---------------- SpMM: 8-lane group per row, 4-deep unrolled gather ----------------
// Each 8-thread group owns one destination row; lane s covers bytes
// [16s,16s+16) of the 128B row. Edge loop is unconditional 4-wide: tail
// slots load a clamped record but get col=0 / wt=0 (row 0 stays L2-hot).
// LAST=false: write bf16 y. LAST=true: out = (a + y1[r] + src[r]) / 3.

template<bool LAST>
__global__ __launch_bounds__(256) void spmm_bf16(
    const int* __restrict__ row_start, const int2* __restrict__ sorted,
    const uint4* __restrict__ src,     // bf16 rows: 8 x uint4 per row
    uint4* __restrict__ y,             // bf16 rows out (!LAST)
    const uint4* __restrict__ y1,      // layer-1 output rows (LAST)
    float4* __restrict__ out)          // f32 final (LAST)
{
    int r = (blockIdx.x * blockDim.x + threadIdx.x) >> 3;
    int s = threadIdx.x & 7;           // 16B slot within row
    if (r >= N_NODES) return;
    int s0 = row_start[r];
    int s1 = row_start[r + 1];

    float a0 = 0.f, a1 = 0.f, a2 = 0.f, a3 = 0.f;
    float a4 = 0.f, a5 = 0.f, a6 = 0.f, a7 = 0.f;

    for (int base = s0; base < s1; base += 4) {
        // clamped record loads (always in-bounds), then tail-neutralized
        int i0 = base;
        int i1 = min(base + 1, N_EDGES - 1);
        int i2 = min(base + 2, N_EDGES - 1);
        int i3 = min(base + 3, N_EDGES - 1);
        int2 e0 = sorted[i0];
        int2 e1 = sorted[i1];
        int2 e2 = sorted[i2];
        int2 e3 = sorted[i3];
        bool v1 = base + 1 < s1, v2 = base + 2 < s1, v3 = base + 3 < s1;
        int   c0 = e0.x;
        int   c1 = v1 ? e1.x : 0;
        int   c2 = v2 ? e2.x : 0;
        int   c3 = v3 ? e3.x : 0;
        float w0 = __int_as_float(e0.y);
        float w1 = v1 ? __int_as_float(e1.y) : 0.f;
        float w2 = v2 ? __int_as_float(e2.y) : 0.f;
        float w3 = v3 ? __int_as_float(e3.y) : 0.f;
        uint4 g0 = src[(size_t)c0 * 8 + s];
        uint4 g1 = src[(size_t)c1 * 8 + s];
        uint4 g2 = src[(size_t)c2 * 8 + s];
        uint4 g3 = src[(size_t)c3 * 8 + s];
#define ACC(vv, wt) \
        a0 = fmaf(wt, bfl(vv.x), a0); a1 = fmaf(wt, bfh(vv.x), a1); \
        a2 = fmaf(wt, bfl(vv.y), a2); a3 = fmaf(wt, bfh(vv.y), a3); \
        a4 = fmaf(wt, bfl(vv.z), a4); a5 = fmaf(wt, bfh(vv.z), a5); \
        a6 = fmaf(wt, bfl(vv.w), a6); a7 = fmaf(wt, bfh(vv.w), a7);
        ACC(g0, w0) ACC(g1, w1) ACC(g2, w2) ACC(g3, w3)
#undef ACC
    }

    if (!LAST) {
        uint4 o;
        o.x = pk(a0, a1); o.y = pk(a2, a3);
        o.z = pk(a4, a5); o.w = pk(a6, a7);
        y[(size_t)r * 8 + s] = o;
    } else {
        // read the two earlier layer outputs for this row (read-once)
        uint4 u1 = y1[(size_t)r * 8 + s];
        uint4 u2 = src[(size_t)r * 8 + s];
        constexpr float sc = 1.0f / 3.0f;
        float4 o0, o1;
        o0.x = (a0 + bfl(u1.x) + bfl(u2.x)) * sc;
        o0.y = (a1 + bfh(u1.x) + bfh(u2.x)) * sc;
        o0.z = (a2 + bfl(u1.y) + bfl(u2.y)) * sc;
        o0.w = (a3 + bfh(u1.y) + bfh(u2.y)) * sc;
        o1.x = (a4 + bfl(u1.z) + bfl(u2.z)) * sc;
        o1.y = (a5 + bfh(u1.z) + bfh(u2.z)) * sc;
        o1.z = (a6 + bfl(u1.w) + bfl(u2.w)) * sc;
        o1.w = (a7 + bfh(u1.w) + bfh(u2.w)) * sc;
        size_t ob = (size_t)r * 16 + 2 * s;
        out[ob]     = o0;
        out[ob + 1] = o1;
    }
}

// ---------------- launch ----------------

extern "C" void kernel_launch(void* const* d_in, const int* in_sizes, int n_in,
                              void* d_out, int out_size, void* d_ws, size_t ws_size,
                              hipStream_t stream) {
    const float* user_emb = (const float*)d_in[0];
    const float* item_emb = (const float*)d_in[1];
    const float* edge_w   = (const float*)d_in[2];
    const int*   edge_row = (const int*)d_in[3];
    const int*   edge_col = (const int*)d_in[4];

    // ws layout: two bf16 embedding buffers + CSR.
    // binned aliases ybuf (binned dead after sort_bucket; ybuf first written
    // by spmm layer 0, which runs after).
    char* p = (char*)d_ws;
    uint4* ebuf = (uint4*)p;        p += (size_t)N_NODES * 8 * sizeof(uint4);   // 25.6 MB
    uint4* ybuf = (uint4*)p;        p += (size_t)N_NODES * 8 * sizeof(uint4);   // 25.6 MB
    int2*  sorted = (int2*)p;       p += (size_t)N_EDGES * sizeof(int2);        // 25.6 MB
    int*   bcnt = (int*)p;          p += (size_t)NBUCK * sizeof(int);
    int*   bbase = (int*)p;         p += (size_t)(NBUCK + 1) * sizeof(int);
    int*   bcursor = (int*)p;       p += (size_t)NBUCK * sizeof(int);
    int*   row_start = (int*)p;     p += (size_t)(N_NODES + 1) * sizeof(int);
    int2*  binned = (int2*)ybuf;    // alias

    hipMemsetAsync(bcnt, 0, (size_t)NBUCK * sizeof(int), stream);

    // fused: coarse histogram (blocks 0..511) + concat->bf16 (rest)
    prep<<<HIST_BLOCKS + CONCAT_BLOCKS, 256, 0, stream>>>(
        edge_row, bcnt, (const float4*)user_emb, (const float4*)item_emb, ebuf);

    scan_buckets<<<1, 1024, 0, stream>>>(bcnt, bbase, bcursor);
    bin_edges<<<NBIN_BLOCKS, BIN_BLOCK, 0, stream>>>(edge_row, edge_col, edge_w,
                                                     bcursor, binned);
    sort_bucket<<<NBUCK, 256, 0, stream>>>(bbase, binned, sorted, row_start);

    int grid = (N_NODES * 8 + 255) / 256;          // 32 rows per 256-thread block
    // layer 0: ebuf -> ybuf (y1)
    spmm_bf16<false><<<grid, 256, 0, stream>>>(row_start, sorted, ebuf, ybuf,
                                               nullptr, nullptr);
    // layer 1: ybuf -> ebuf (y2; ebuf dead after layer 0)
    spmm_bf16<false><<<grid, 256, 0, stream>>>(row_start, sorted, ybuf, ebuf,
                                               nullptr, nullptr);
    // layer 2: src=ebuf (y2), epilogue reads ybuf (y1) + ebuf rows, writes out
    spmm_bf16<true><<<grid, 256, 0, stream>>>(row_start, sorted, ebuf, nullptr,
                                              ybuf, (float4*)d_out);
}

// Round 6
// 404.324 us; speedup vs baseline: 1.4030x; 1.0290x over previous
//
#include <hip/hip_runtime.h>
#include <hip/hip_bf16.h>

// LightGCN: 3 layers of SpMM on 200000x64 embeddings, 3.2M edges.
// R10: spmm - LDS record staging + 8-deep gather MLP. Block = 32 rows whose
//      records are one contiguous `sorted` range (mean 512 edges, 12KB):
//      stage row_start[33] + records into LDS coalesced (kills the 8x
//      redundant per-lane record loads and takes the 200cy L2 record load
//      off the gather addr-dep chain), unroll 4->8 (8 gathers in flight
//      per lane). Global-path fallback if a block exceeds 1536 edges.
//      CSR build frozen from R9.
// R9:  bin_edges block-local counting sort + coalesced run flush.
// R8:  spmm 8-lane-group-per-row, unconditional unrolled gather.
// R7:  no f32 acc RMW (layer2 fuses out=(a+y1+y2)/3).
// R5:  two-level counting-sort CSR build.

constexpr int NUM_USERS = 100000;
constexpr int NUM_ITEMS = 100000;
constexpr int N_NODES   = NUM_USERS + NUM_ITEMS;   // 200000
constexpr int EMB       = 64;
constexpr int N_EDGES   = 3200000;

constexpr int BUCK_SHIFT = 8;                       // 256 rows per bucket
constexpr int NBUCK = (N_NODES + 255) >> BUCK_SHIFT; // 782
constexpr int BIN_BLOCK = 512;
constexpr int EPB = 8192;                            // edges per bin block
constexpr int NBIN_BLOCKS = (N_EDGES + EPB - 1) / EPB; // 391
constexpr int SORT_CAP = 6144;                       // mean 4096, sigma 64

constexpr int HIST_BLOCKS   = 512;
constexpr int CONCAT_BLOCKS = (N_NODES * 8 + 255) / 256; // 6250

constexpr int ROWS_PER_BLOCK = 32;                   // spmm
constexpr int ECAP = 1536;                           // LDS record cap (mean 512)

// ---------------- bf16 helpers ----------------

__device__ __forceinline__ float bfl(unsigned u) { return __uint_as_float(u << 16); }
__device__ __forceinline__ float bfh(unsigned u) { return __uint_as_float(u & 0xFFFF0000u); }
__device__ __forceinline__ unsigned f2bf(float f) {          // RNE
    unsigned u = __float_as_uint(f);
    return (u + 0x7FFFu + ((u >> 16) & 1u)) >> 16;
}
__device__ __forceinline__ unsigned pk(float lo, float hi) {
    return f2bf(lo) | (f2bf(hi) << 16);
}

// ---------------- prep: coarse histogram + concat->bf16 (fused, independent) ----------------

__global__ __launch_bounds__(256) void prep(
    const int* __restrict__ row, int* __restrict__ bcnt,
    const float4* __restrict__ u, const float4* __restrict__ it,
    uint4* __restrict__ ebuf) {
    __shared__ int h[NBUCK];
    if (blockIdx.x < HIST_BLOCKS) {
        for (int i = threadIdx.x; i < NBUCK; i += 256) h[i] = 0;
        __syncthreads();
        int nt = HIST_BLOCKS * 256;
        for (int e = blockIdx.x * 256 + threadIdx.x; e < N_EDGES; e += nt) {
            int r = __builtin_nontemporal_load(&row[e]);
            atomicAdd(&h[r >> BUCK_SHIFT], 1);
        }
        __syncthreads();
        for (int i = threadIdx.x; i < NBUCK; i += 256) {
            int c = h[i];
            if (c) atomicAdd(&bcnt[i], c);
        }
    } else {
        int i = (blockIdx.x - HIST_BLOCKS) * 256 + threadIdx.x;
        if (i >= N_NODES * 8) return;
        const float4* s = (i < NUM_USERS * 8) ? (u + 2 * (size_t)i)
                                              : (it + 2 * ((size_t)i - (size_t)NUM_USERS * 8));
        float4 f0 = s[0], f1 = s[1];
        uint4 o;
        o.x = pk(f0.x, f0.y); o.y = pk(f0.z, f0.w);
        o.z = pk(f1.x, f1.y); o.w = pk(f1.z, f1.w);
        ebuf[i] = o;
    }
}

// ---------------- CSR build: two-level counting sort ----------------

// Exclusive scan of 782 bucket counts -> bucket bases + cursors.
__global__ __launch_bounds__(1024) void scan_buckets(const int* __restrict__ bcnt,
                                                     int* __restrict__ bbase,
                                                     int* __restrict__ bcursor) {
    __shared__ int lds[1024];
    int t = threadIdx.x;
    int v = (t < NBUCK) ? bcnt[t] : 0;
    lds[t] = v;
    __syncthreads();
    for (int off = 1; off < 1024; off <<= 1) {
        int x = (t >= off) ? lds[t - off] : 0;
        __syncthreads();
        lds[t] += x;
        __syncthreads();
    }
    int excl = lds[t] - v;
    if (t < NBUCK) { bbase[t] = excl; bcursor[t] = excl; }
    if (t == 0) bbase[NBUCK] = N_EDGES;
}

// Bin edges into coarse buckets, block-local counting sort in LDS, then
// coalesced run flush (8 lanes x 8B consecutive per bucket run).
// Record: { col | (row&255)<<18 , w_bits }  (col < 2^18, rlow 8 bits).
__global__ __launch_bounds__(BIN_BLOCK) void bin_edges(
    const int* __restrict__ row, const int* __restrict__ col,
    const float* __restrict__ w,
    int* __restrict__ bcursor, int2* __restrict__ binned) {
    __shared__ int2 stage[EPB];          // 64 KB
    __shared__ int  hcnt[NBUCK];
    __shared__ int  hbase[NBUCK];
    __shared__ int  cursor[NBUCK];
    __shared__ int  lds2[BIN_BLOCK];
    int t = threadIdx.x;
    int e0 = blockIdx.x * EPB;
    int e1 = e0 + EPB; if (e1 > N_EDGES) e1 = N_EDGES;

    // A) local histogram (plain row load so chunk stays L2-hot for phase C)
    for (int i = t; i < NBUCK; i += BIN_BLOCK) hcnt[i] = 0;
    __syncthreads();
    for (int e = e0 + t; e < e1; e += BIN_BLOCK)
        atomicAdd(&hcnt[row[e] >> BUCK_SHIFT], 1);
    __syncthreads();

    // B1) global reservation
    for (int i = t; i < NBUCK; i += BIN_BLOCK) {
        int c = hcnt[i];
        hbase[i] = c ? atomicAdd(&bcursor[i], c) : 0;
    }
    // B2) local exclusive scan of hcnt -> cursor (pairs of 2 per thread)
    int i0 = 2 * t, i1 = 2 * t + 1;
    int c0 = (i0 < NBUCK) ? hcnt[i0] : 0;
    int c1 = (i1 < NBUCK) ? hcnt[i1] : 0;
    lds2[t] = c0 + c1;
    __syncthreads();
    for (int off = 1; off < BIN_BLOCK; off <<= 1) {
        int x = (t >= off) ? lds2[t - off] : 0;
        __syncthreads();
        lds2[t] += x;
        __syncthreads();
    }
    int pairExcl = lds2[t] - (c0 + c1);
    if (i0 < NBUCK) cursor[i0] = pairExcl;
    if (i1 < NBUCK) cursor[i1] = pairExcl + c0;
    __syncthreads();

    // C) stage records sorted by bucket
    for (int e = e0 + t; e < e1; e += BIN_BLOCK) {
        int r  = row[e];                 // L2-hot
        int bk = r >> BUCK_SHIFT;
        int pos = atomicAdd(&cursor[bk], 1);
        stage[pos] = make_int2(__builtin_nontemporal_load(&col[e]) | ((r & 255) << 18),
                               __float_as_int(__builtin_nontemporal_load(&w[e])));
    }
    __syncthreads();

    // D) flush runs: 8 lanes per bucket, 8 buckets per wave
    int wave = t >> 6;
    int lane = t & 63;
    int sl   = lane & 7;
    constexpr int NWAVE = BIN_BLOCK / 64;
    for (int base = wave * 8; base < NBUCK; base += NWAVE * 8) {
        int bk = base + (lane >> 3);
        if (bk < NBUCK) {
            int c  = hcnt[bk];
            int st = cursor[bk] - c;     // cursor now = local end
            int gp = hbase[bk];
            for (int j = sl; j < c; j += 8)
                binned[gp + j] = stage[st + j];
        }
    }
}

// One block per bucket. LDS counting sort by row-within-bucket,
// emits row_start, stages sorted records in LDS, coalesced streamout.
__global__ __launch_bounds__(256) void sort_bucket(
    const int* __restrict__ bbase, const int2* __restrict__ binned,
    int2* __restrict__ sorted, int* __restrict__ row_start) {
    __shared__ int cnt[256];
    __shared__ int sc[256];
    __shared__ int2 buf[SORT_CAP];
    int b = blockIdx.x, t = threadIdx.x;
    int gb = bbase[b];
    int n  = bbase[b + 1] - gb;

    cnt[t] = 0;
    __syncthreads();
    for (int i = t; i < n; i += 256)
        atomicAdd(&cnt[binned[gb + i].x >> 18], 1);
    __syncthreads();

    // exclusive scan of cnt[256]
    int v = cnt[t];
    sc[t] = v;
    __syncthreads();
    for (int off = 1; off < 256; off <<= 1) {
        int x = (t >= off) ? sc[t - off] : 0;
        __syncthreads();
        sc[t] += x;
        __syncthreads();
    }
    int excl = sc[t] - v;

    int r = (b << BUCK_SHIFT) + t;
    if (r < N_NODES) row_start[r] = gb + excl;
    if (b == NBUCK - 1 && t == 0) row_start[N_NODES] = N_EDGES;
    __syncthreads();
    cnt[t] = excl;                        // reuse as running cursor
    __syncthreads();

    for (int i = t; i < n; i += 256) {
        int2 rec = binned[gb + i];        // L2-hot (read in phase 1)
        int rl = rec.x >> 18;
        int k = atomicAdd(&cnt[rl], 1);
        if (k < SORT_CAP)
            buf[k] = make_int2(rec.x & 0x3FFFF, rec.y);
    }
    __syncthreads();
    int m = n < SORT_CAP ? n : SORT_CAP;
    for (int i = t; i < m; i += 256)
        sorted[gb + i] = buf[i];
}

// ---------------- SpMM: LDS-staged records, 8-lane group per row, 8-deep ----------------
// Block = 32 consecutive rows; their records are a contiguous `sorted`
// range (mean 512). Stage row_start[33] + records into LDS coalesced;
// each 8-thread group owns one row (lane = 16B slot of the 128B row),
// 8-deep unconditional gather loop (tail slots -> col 0 / wt 0).
// LAST=false: write bf16 y. LAST=true: out = (a + y1[r] + src[r]) / 3.

template<bool LAST>
__global__ __launch_bounds__(256) void spmm_bf16(
    const int* __restrict__ row_start, const int2* __restrict__ sorted,
    const uint4* __restrict__ src,     // bf16 rows: 8 x uint4 per row
    uint4* __restrict__ y,             // bf16 rows out (!LAST)
    const uint4* __restrict__ y1,      // layer-1 output rows (LAST)
    float4* __restrict__ out)          // f32 final (LAST)
{
    __shared__ int2 erec[ECAP];
    __shared__ int  rs[ROWS_PER_BLOCK + 1];
    int t  = threadIdx.x;
    int R0 = blockIdx.x * ROWS_PER_BLOCK;
    if (t <= ROWS_PER_BLOCK) rs[t] = row_start[R0 + t];
    __syncthreads();
    int eb0 = rs[0];
    int n   = rs[ROWS_PER_BLOCK] - eb0;

    int g = t >> 3;                    // row within block (0..31)
    int s = t & 7;                     // 16B slot within row
    int r = R0 + g;
    int s0 = rs[g], s1 = rs[g + 1];
    int cnt = s1 - s0;

    float a0 = 0.f, a1 = 0.f, a2 = 0.f, a3 = 0.f;
    float a4 = 0.f, a5 = 0.f, a6 = 0.f, a7 = 0.f;

#define ACC(vv, wt) \
    a0 = fmaf(wt, bfl(vv.x), a0); a1 = fmaf(wt, bfh(vv.x), a1); \
    a2 = fmaf(wt, bfl(vv.y), a2); a3 = fmaf(wt, bfh(vv.y), a3); \
    a4 = fmaf(wt, bfl(vv.z), a4); a5 = fmaf(wt, bfh(vv.z), a5); \
    a6 = fmaf(wt, bfl(vv.w), a6); a7 = fmaf(wt, bfh(vv.w), a7);

    if (n <= ECAP) {
        // stage the block's contiguous record range (each record once)
        for (int i = t; i < n; i += 256) erec[i] = sorted[eb0 + i];
        __syncthreads();
        int lb = s0 - eb0;
        for (int k = 0; k < cnt; k += 8) {
            int   c[8]; float wv[8]; uint4 gr[8];
#pragma unroll
            for (int j = 0; j < 8; ++j) {
                int lk = k + j;
                bool v = lk < cnt;
                int2 e = erec[lb + (v ? lk : 0)];
                c[j]  = v ? e.x : 0;
                wv[j] = v ? __int_as_float(e.y) : 0.f;
            }
#pragma unroll
            for (int j = 0; j < 8; ++j) gr[j] = src[(size_t)c[j] * 8 + s];
#pragma unroll
            for (int j = 0; j < 8; ++j) { ACC(gr[j], wv[j]) }
        }
    } else {
        // fallback: direct-global 8-deep (practically never taken)
        for (int k = 0; k < cnt; k += 8) {
            int   c[8]; float wv[8]; uint4 gr[8];
#pragma unroll
            for (int j = 0; j < 8; ++j) {
                int lk = k + j;
                bool v = lk < cnt;
                int2 e = sorted[s0 + (v ? lk : 0)];
                c[j]  = v ? e.x : 0;
                wv[j] = v ? __int_as_float(e.y) : 0.f;
            }
#pragma unroll
            for (int j = 0; j < 8; ++j) gr[j] = src[(size_t)c[j] * 8 + s];
#pragma unroll
            for (int j = 0; j < 8; ++j) { ACC(gr[j], wv[j]) }
        }
    }
#undef ACC

    if (!LAST) {
        uint4 o;
        o.x = pk(a0, a1); o.y = pk(a2, a3);
        o.z = pk(a4, a5); o.w = pk(a6, a7);
        y[(size_t)r * 8 + s] = o;
    } else {
        // read the two earlier layer outputs for this row (read-once)
        uint4 u1 = y1[(size_t)r * 8 + s];
        uint4 u2 = src[(size_t)r * 8 + s];
        constexpr float sc = 1.0f / 3.0f;
        float4 o0, o1;
        o0.x = (a0 + bfl(u1.x) + bfl(u2.x)) * sc;
        o0.y = (a1 + bfh(u1.x) + bfh(u2.x)) * sc;
        o0.z = (a2 + bfl(u1.y) + bfl(u2.y)) * sc;
        o0.w = (a3 + bfh(u1.y) + bfh(u2.y)) * sc;
        o1.x = (a4 + bfl(u1.z) + bfl(u2.z)) * sc;
        o1.y = (a5 + bfh(u1.z) + bfh(u2.z)) * sc;
        o1.z = (a6 + bfl(u1.w) + bfl(u2.w)) * sc;
        o1.w = (a7 + bfh(u1.w) + bfh(u2.w)) * sc;
        size_t ob = (size_t)r * 16 + 2 * s;
        out[ob]     = o0;
        out[ob + 1] = o1;
    }
}

// ---------------- launch ----------------

extern "C" void kernel_launch(void* const* d_in, const int* in_sizes, int n_in,
                              void* d_out, int out_size, void* d_ws, size_t ws_size,
                              hipStream_t stream) {
    const float* user_emb = (const float*)d_in[0];
    const float* item_emb = (const float*)d_in[1];
    const float* edge_w   = (const float*)d_in[2];
    const int*   edge_row = (const int*)d_in[3];
    const int*   edge_col = (const int*)d_in[4];

    // ws layout: two bf16 embedding buffers + CSR.
    // binned aliases ybuf (binned dead after sort_bucket; ybuf first written
    // by spmm layer 0, which runs after).
    char* p = (char*)d_ws;
    uint4* ebuf = (uint4*)p;        p += (size_t)N_NODES * 8 * sizeof(uint4);   // 25.6 MB
    uint4* ybuf = (uint4*)p;        p += (size_t)N_NODES * 8 * sizeof(uint4);   // 25.6 MB
    int2*  sorted = (int2*)p;       p += (size_t)N_EDGES * sizeof(int2);        // 25.6 MB
    int*   bcnt = (int*)p;          p += (size_t)NBUCK * sizeof(int);
    int*   bbase = (int*)p;         p += (size_t)(NBUCK + 1) * sizeof(int);
    int*   bcursor = (int*)p;       p += (size_t)NBUCK * sizeof(int);
    int*   row_start = (int*)p;     p += (size_t)(N_NODES + 1) * sizeof(int);
    int2*  binned = (int2*)ybuf;    // alias

    hipMemsetAsync(bcnt, 0, (size_t)NBUCK * sizeof(int), stream);

    // fused: coarse histogram (blocks 0..511) + concat->bf16 (rest)
    prep<<<HIST_BLOCKS + CONCAT_BLOCKS, 256, 0, stream>>>(
        edge_row, bcnt, (const float4*)user_emb, (const float4*)item_emb, ebuf);

    scan_buckets<<<1, 1024, 0, stream>>>(bcnt, bbase, bcursor);
    bin_edges<<<NBIN_BLOCKS, BIN_BLOCK, 0, stream>>>(edge_row, edge_col, edge_w,
                                                     bcursor, binned);
    sort_bucket<<<NBUCK, 256, 0, stream>>>(bbase, binned, sorted, row_start);

    int grid = N_NODES / ROWS_PER_BLOCK;           // 6250 blocks, 32 rows each
    // layer 0: ebuf -> ybuf (y1)
    spmm_bf16<false><<<grid, 256, 0, stream>>>(row_start, sorted, ebuf, ybuf,
                                               nullptr, nullptr);
    // layer 1: ybuf -> ebuf (y2; ebuf dead after layer 0)
    spmm_bf16<false><<<grid, 256, 0, stream>>>(row_start, sorted, ybuf, ebuf,
                                               nullptr, nullptr);
    // layer 2: src=ebuf (y2), epilogue reads ybuf (y1) + ebuf rows, writes out
    spmm_bf16<true><<<grid, 256, 0, stream>>>(row_start, sorted, ebuf, nullptr,
                                              ybuf, (float4*)d_out);
}